// Round 10
// baseline (651.407 us; speedup 1.0000x reference)
//
#include <hip/hip_runtime.h>
#include <hip/hip_fp16.h>
#include <hip/hip_bf16.h>

// LightGCN propagation on MI355X (gfx950).
// out = (h0 + A*h0 + A^2*h0 + A^3*h0)/4, A = COO(edge_row, edge_col, edge_val)
//
// Round 13: spmm MLP ladder continues to pay (4 gathers: 165us -> 8: 144 ->
// 16 (pair-row): 122, BW 3.0 -> 4.04 TB/s, traffic constant). Quad-row:
// 4 adjacent rows/wave, joint loop issues 32 gathers before any FMA
// (unrolled arrays, compile-time indices -> registers), 8-deep tails.
// Everything else byte-identical to round 12 (632 us) to isolate the effect.
// Build (verified): partition_arena @1024thr (block-owned runs) -> arena_scan
// -> fine_scatter (LDS-staged 512-row bins) -> row-sorted CSR + row_ptr.
// Propagation (verified): init16 -> spmm_mid x2 -> spmm_last fused
// out = (emb + h1 + h2 + A*h2) * 0.25, single NT write.
// word = val<<32 | col<<9 | row_local9; spmm unpacks col = lo >> 9.

#define NUM_USERS 200000
#define NUM_ITEMS 100000
#define N_NODES   300000
#define EMB_DIM   64
#define NNZ       5000000

#define COARSE_SHIFT 9
#define COARSE_ROWS  512
#define NCOARSE      ((N_NODES + COARSE_ROWS - 1) / COARSE_ROWS)  // 586

#define ARENA_CAP 12288   // per-bin slots; mean 8532, sigma ~92 -> +40 sigma
#define FS_CAP    9216    // LDS-staged bin cap; mean+7.4 sigma, fallback below
#define FS_SHMEM  (FS_CAP * 8 + 2 * COARSE_ROWS * 4)              // 77824 B

#define P1_CHUNK  16384
#define P1_BLOCKS ((NNZ + P1_CHUNK - 1) / P1_CHUNK)               // 306
#define P1_THREADS 1024

typedef unsigned long long u64;

// ---------------------------------------------------------------------------
// init: h0 = ego (fp16, 4 dims packed per uint2). No out write.
// ---------------------------------------------------------------------------
__global__ void init16_kernel(const float4* __restrict__ user_emb,
                              const float4* __restrict__ item_emb,
                              uint2* __restrict__ h16) {
    const int n4 = N_NODES * (EMB_DIM / 4);
    int idx = blockIdx.x * blockDim.x + threadIdx.x;
    if (idx >= n4) return;
    const int user4 = NUM_USERS * (EMB_DIM / 4);
    float4 v = (idx < user4) ? user_emb[idx] : item_emb[idx - user4];
    __half2 p0 = __floats2half2_rn(v.x, v.y);
    __half2 p1 = __floats2half2_rn(v.z, v.w);
    uint2 u;
    u.x = *(unsigned int*)&p0;
    u.y = *(unsigned int*)&p1;
    h16[idx] = u;
}

// ---------------------------------------------------------------------------
// zero ints (counts / cursors)
// ---------------------------------------------------------------------------
__global__ void zero_int_kernel(int* __restrict__ p, int n) {
    int idx = blockIdx.x * blockDim.x + threadIdx.x;
    if (idx < n) p[idx] = 0;
}

// ---------------------------------------------------------------------------
// pass 1: partition edges into 586 fixed-stride bin arenas (512 rows/bin).
// Per (block, bin): LDS hist -> one global atomicAdd reserves a contiguous
// run in arena[bin*CAP ...]; all stores of a run come from this block -> one
// XCD owns each run -> full-line writebacks. 1024 threads/block (r12: 142us
// @256thr/10.6% occ -> below 122us cutoff @1024thr).
// word = val<<32 | col<<9 | row_local9
// ---------------------------------------------------------------------------
__global__ void __launch_bounds__(P1_THREADS)
partition_arena(const int* __restrict__ row,
                const int* __restrict__ col,
                const float* __restrict__ val,
                int* __restrict__ ccur,
                u64* __restrict__ arena) {
    __shared__ int hist[NCOARSE];
    __shared__ int lbase[NCOARSE];
    __shared__ int lcur[NCOARSE];
    int t = threadIdx.x;
    int start = blockIdx.x * P1_CHUNK;
    int end = min(start + P1_CHUNK, NNZ);
    for (int j = t; j < NCOARSE; j += P1_THREADS) { hist[j] = 0; lcur[j] = 0; }
    __syncthreads();
    for (int i = start + t; i < end; i += P1_THREADS)
        atomicAdd(&hist[(unsigned int)row[i] >> COARSE_SHIFT], 1);
    __syncthreads();
    for (int j = t; j < NCOARSE; j += P1_THREADS) {
        int c = hist[j];
        if (c > 0)
            lbase[j] = j * ARENA_CAP + atomicAdd(&ccur[j], c);
    }
    __syncthreads();
    for (int i = start + t; i < end; i += P1_THREADS) {
        int r = row[i];
        int b = (int)((unsigned int)r >> COARSE_SHIFT);
        unsigned int lo = ((unsigned int)col[i] << 9) | ((unsigned int)r & 511u);
        u64 p = ((u64)__float_as_uint(val[i]) << 32) | (u64)lo;
        int pos = lbase[b] + atomicAdd(&lcur[b], 1);
        arena[pos] = p;
    }
}

// ---------------------------------------------------------------------------
// exclusive scan of 586 final bin counts -> cbase[0..586] (cbase[586] = NNZ)
// ---------------------------------------------------------------------------
__global__ void __launch_bounds__(1024)
arena_scan(const int* __restrict__ cnt, int* __restrict__ cbase) {
    __shared__ int lds[1024];
    int t = threadIdx.x;
    lds[t] = (t < NCOARSE) ? cnt[t] : 0;
    __syncthreads();
    for (int off = 1; off < 1024; off <<= 1) {
        int v = (t >= off) ? lds[t - off] : 0;
        __syncthreads();
        lds[t] += v;
        __syncthreads();
    }
    if (t < NCOARSE) cbase[t] = (t > 0) ? lds[t - 1] : 0;
    if (t == 0) cbase[NCOARSE] = lds[NCOARSE - 1];
}

// ---------------------------------------------------------------------------
// pass 2: one block per 512-row bin. Stage the bin's arena region ONCE in
// dynamic LDS, LDS hist by row_local -> block scan -> row_ptr, then scatter
// LDS -> final row-sorted CSR (block-private ~70KB window). Fallback branch:
// global two-pass for (statistically unreachable) n > FS_CAP.
// ---------------------------------------------------------------------------
__global__ void __launch_bounds__(1024)
fine_scatter(const int* __restrict__ cbase,
             const int* __restrict__ cnt,
             const u64* __restrict__ arena,
             u64* __restrict__ csr,
             int* __restrict__ row_ptr) {
    extern __shared__ u64 smem[];
    u64* buf  = smem;
    int* offs = (int*)&smem[FS_CAP];
    int* cur  = offs + COARSE_ROWS;
    int t = threadIdx.x;
    int bin = blockIdx.x;
    int n = cnt[bin];
    int cstart = cbase[bin];
    const u64* src = arena + (size_t)bin * ARENA_CAP;
    if (t < COARSE_ROWS) { offs[t] = 0; cur[t] = 0; }
    __syncthreads();
    if (n <= FS_CAP) {
        for (int i = t; i < n; i += 1024) {
            u64 p = src[i];
            buf[i] = p;
            atomicAdd(&offs[(unsigned int)p & 511u], 1);
        }
        __syncthreads();
        int c = (t < COARSE_ROWS) ? offs[t] : 0;
        for (int off = 1; off < COARSE_ROWS; off <<= 1) {
            int v = (t >= off && t < COARSE_ROWS) ? offs[t - off] : 0;
            __syncthreads();
            if (t < COARSE_ROWS) offs[t] += v;
            __syncthreads();
        }
        int excl = (t < COARSE_ROWS) ? offs[t] - c : 0;
        __syncthreads();
        if (t < COARSE_ROWS) offs[t] = excl;
        __syncthreads();
        int r = (bin << COARSE_SHIFT) + t;
        if (t < COARSE_ROWS && r < N_NODES) row_ptr[r] = cstart + excl;
        if (bin == NCOARSE - 1 && t == 0) row_ptr[N_NODES] = cbase[NCOARSE];
        for (int i = t; i < n; i += 1024) {
            u64 p = buf[i];
            int rl = (int)((unsigned int)p & 511u);
            int pos = cstart + offs[rl] + atomicAdd(&cur[rl], 1);
            csr[pos] = p;
        }
    } else {
        // fallback: global two-pass (same semantics, no LDS staging)
        for (int i = t; i < n; i += 1024)
            atomicAdd(&offs[(unsigned int)src[i] & 511u], 1);
        __syncthreads();
        int c = (t < COARSE_ROWS) ? offs[t] : 0;
        for (int off = 1; off < COARSE_ROWS; off <<= 1) {
            int v = (t >= off && t < COARSE_ROWS) ? offs[t - off] : 0;
            __syncthreads();
            if (t < COARSE_ROWS) offs[t] += v;
            __syncthreads();
        }
        int excl = (t < COARSE_ROWS) ? offs[t] - c : 0;
        __syncthreads();
        if (t < COARSE_ROWS) offs[t] = excl;
        __syncthreads();
        int r = (bin << COARSE_SHIFT) + t;
        if (t < COARSE_ROWS && r < N_NODES) row_ptr[r] = cstart + excl;
        if (bin == NCOARSE - 1 && t == 0) row_ptr[N_NODES] = cbase[NCOARSE];
        for (int i = t; i < n; i += 1024) {
            u64 p = src[i];
            int rl = (int)((unsigned int)p & 511u);
            int pos = cstart + offs[rl] + atomicAdd(&cur[rl], 1);
            csr[pos] = p;
        }
    }
}

// ---------------------------------------------------------------------------
// gather cores. edge word: val<<32 | col<<9 | row_local9 -> col = low32 >> 9
// tail: single row, 8/4/1-deep. quad: 4 adjacent rows, 32 gathers in flight.
// All array indices are compile-time (full unroll) -> registers, no scratch.
// ---------------------------------------------------------------------------
__device__ __forceinline__ void tail_accum(const u64* __restrict__ csr,
                                           const __half* __restrict__ x,
                                           int lane, int k, int e, float& acc) {
    for (; k + 8 <= e; k += 8) {
        u64 P[8];
#pragma unroll
        for (int j = 0; j < 8; ++j) P[j] = csr[k + j];
        float X[8];
#pragma unroll
        for (int j = 0; j < 8; ++j)
            X[j] = __half2float(x[(((unsigned int)P[j] >> 9) << 6) + lane]);
#pragma unroll
        for (int j = 0; j < 8; ++j)
            acc += __uint_as_float((unsigned int)(P[j] >> 32)) * X[j];
    }
    for (; k + 4 <= e; k += 4) {
        u64 P[4];
#pragma unroll
        for (int j = 0; j < 4; ++j) P[j] = csr[k + j];
        float X[4];
#pragma unroll
        for (int j = 0; j < 4; ++j)
            X[j] = __half2float(x[(((unsigned int)P[j] >> 9) << 6) + lane]);
#pragma unroll
        for (int j = 0; j < 4; ++j)
            acc += __uint_as_float((unsigned int)(P[j] >> 32)) * X[j];
    }
    for (; k < e; ++k) {
        u64 p = csr[k];
        acc += __uint_as_float((unsigned int)(p >> 32))
             * __half2float(x[(((unsigned int)p >> 9) << 6) + lane]);
    }
}

__device__ __forceinline__ void quad_accum(const int* __restrict__ row_ptr,
                                           const u64* __restrict__ csr,
                                           const __half* __restrict__ x,
                                           int lane, int r0,
                                           float& acc0, float& acc1,
                                           float& acc2, float& acc3) {
    int b0 = row_ptr[r0];
    int b1 = row_ptr[r0 + 1];
    int b2 = row_ptr[r0 + 2];
    int b3 = row_ptr[r0 + 3];
    int b4 = row_ptr[r0 + 4];
    int k0 = b0, k1 = b1, k2 = b2, k3 = b3;
    while (k0 + 8 <= b1 && k1 + 8 <= b2 && k2 + 8 <= b3 && k3 + 8 <= b4) {
        u64 P0[8], P1[8], P2[8], P3[8];
#pragma unroll
        for (int j = 0; j < 8; ++j) P0[j] = csr[k0 + j];
#pragma unroll
        for (int j = 0; j < 8; ++j) P1[j] = csr[k1 + j];
#pragma unroll
        for (int j = 0; j < 8; ++j) P2[j] = csr[k2 + j];
#pragma unroll
        for (int j = 0; j < 8; ++j) P3[j] = csr[k3 + j];
        float X0[8], X1[8], X2[8], X3[8];
#pragma unroll
        for (int j = 0; j < 8; ++j)
            X0[j] = __half2float(x[(((unsigned int)P0[j] >> 9) << 6) + lane]);
#pragma unroll
        for (int j = 0; j < 8; ++j)
            X1[j] = __half2float(x[(((unsigned int)P1[j] >> 9) << 6) + lane]);
#pragma unroll
        for (int j = 0; j < 8; ++j)
            X2[j] = __half2float(x[(((unsigned int)P2[j] >> 9) << 6) + lane]);
#pragma unroll
        for (int j = 0; j < 8; ++j)
            X3[j] = __half2float(x[(((unsigned int)P3[j] >> 9) << 6) + lane]);
#pragma unroll
        for (int j = 0; j < 8; ++j)
            acc0 += __uint_as_float((unsigned int)(P0[j] >> 32)) * X0[j];
#pragma unroll
        for (int j = 0; j < 8; ++j)
            acc1 += __uint_as_float((unsigned int)(P1[j] >> 32)) * X1[j];
#pragma unroll
        for (int j = 0; j < 8; ++j)
            acc2 += __uint_as_float((unsigned int)(P2[j] >> 32)) * X2[j];
#pragma unroll
        for (int j = 0; j < 8; ++j)
            acc3 += __uint_as_float((unsigned int)(P3[j] >> 32)) * X3[j];
        k0 += 8; k1 += 8; k2 += 8; k3 += 8;
    }
    tail_accum(csr, x, lane, k0, b1, acc0);
    tail_accum(csr, x, lane, k1, b2, acc1);
    tail_accum(csr, x, lane, k2, b3, acc2);
    tail_accum(csr, x, lane, k3, b4, acc3);
}

// ---------------------------------------------------------------------------
// pull SpMM mid-layer: four rows per wave, lane = dim. Writes y only.
// ---------------------------------------------------------------------------
__global__ void spmm_mid_kernel(const int* __restrict__ row_ptr,
                                const u64* __restrict__ csr,
                                const __half* __restrict__ x,
                                __half* __restrict__ y) {
    int gid  = blockIdx.x * blockDim.x + threadIdx.x;
    int r0   = (gid >> 6) * 4;
    int lane = threadIdx.x & 63;
    if (r0 >= N_NODES) return;
    r0 = __builtin_amdgcn_readfirstlane(r0);  // force SGPR: scalar edge loads
    float acc0 = 0.f, acc1 = 0.f, acc2 = 0.f, acc3 = 0.f;
    quad_accum(row_ptr, csr, x, lane, r0, acc0, acc1, acc2, acc3);
    int o = (r0 << 6) + lane;
    y[o]       = __float2half(acc0);
    y[o + 64]  = __float2half(acc1);
    y[o + 128] = __float2half(acc2);
    y[o + 192] = __float2half(acc3);
}

// ---------------------------------------------------------------------------
// pull SpMM last layer, fused combine (four rows per wave):
// out = (h0(emb fp32) + h1 + h2 + A*h2) * 0.25, single NT write, no y.
// ---------------------------------------------------------------------------
__global__ void spmm_last_kernel(const int* __restrict__ row_ptr,
                                 const u64* __restrict__ csr,
                                 const __half* __restrict__ x,    // h2
                                 const __half* __restrict__ h1,
                                 const float* __restrict__ user_emb,
                                 const float* __restrict__ item_emb,
                                 float* __restrict__ out) {
    int gid  = blockIdx.x * blockDim.x + threadIdx.x;
    int r0   = (gid >> 6) * 4;
    int lane = threadIdx.x & 63;
    if (r0 >= N_NODES) return;
    r0 = __builtin_amdgcn_readfirstlane(r0);  // force SGPR: scalar edge loads
    float acc0 = 0.f, acc1 = 0.f, acc2 = 0.f, acc3 = 0.f;
    quad_accum(row_ptr, csr, x, lane, r0, acc0, acc1, acc2, acc3);
    float accs[4] = {acc0, acc1, acc2, acc3};
    int obase = (r0 << 6) + lane;
#pragma unroll
    for (int j = 0; j < 4; ++j) {
        int o = obase + j * 64;
        float h0v = (o < NUM_USERS * EMB_DIM) ? user_emb[o]
                                              : item_emb[o - NUM_USERS * EMB_DIM];
        float v = (h0v + __half2float(h1[o]) + __half2float(x[o]) + accs[j]) * 0.25f;
        __builtin_nontemporal_store(v, &out[o]);
    }
}

// ---------------------------------------------------------------------------
// fallback (round-1 push path) if ws too small
// ---------------------------------------------------------------------------
__global__ void init32_kernel(const float4* __restrict__ user_emb,
                              const float4* __restrict__ item_emb,
                              float4* __restrict__ h,
                              float4* __restrict__ out) {
    const int n4 = N_NODES * (EMB_DIM / 4);
    int idx = blockIdx.x * blockDim.x + threadIdx.x;
    if (idx >= n4) return;
    const int user4 = NUM_USERS * (EMB_DIM / 4);
    float4 v = (idx < user4) ? user_emb[idx] : item_emb[idx - user4];
    h[idx] = v;
    out[idx] = v;
}
__global__ void zero4_kernel(float4* __restrict__ p) {
    const int n4 = N_NODES * (EMB_DIM / 4);
    int idx = blockIdx.x * blockDim.x + threadIdx.x;
    if (idx < n4) p[idx] = make_float4(0.f, 0.f, 0.f, 0.f);
}
__global__ void spmm_push_kernel(const int* __restrict__ row, const int* __restrict__ col,
                                 const float* __restrict__ val, const float* __restrict__ x,
                                 float* __restrict__ y) {
    unsigned int gid = blockIdx.x * blockDim.x + threadIdx.x;
    unsigned int e = gid >> 6, lane = gid & 63u;
    if (e >= NNZ) return;
    atomicAdd(&y[(unsigned int)row[e] * EMB_DIM + lane],
              val[e] * x[(unsigned int)col[e] * EMB_DIM + lane]);
}
__global__ void acc_kernel(float4* __restrict__ out, const float4* __restrict__ h, float scale) {
    const int n4 = N_NODES * (EMB_DIM / 4);
    int idx = blockIdx.x * blockDim.x + threadIdx.x;
    if (idx >= n4) return;
    float4 o = out[idx], a = h[idx];
    o.x = (o.x + a.x) * scale; o.y = (o.y + a.y) * scale;
    o.z = (o.z + a.z) * scale; o.w = (o.w + a.w) * scale;
    out[idx] = o;
}

extern "C" void kernel_launch(void* const* d_in, const int* in_sizes, int n_in,
                              void* d_out, int out_size, void* d_ws, size_t ws_size,
                              hipStream_t stream) {
    const float* user_emb = (const float*)d_in[0];
    const float* item_emb = (const float*)d_in[1];
    const int*   edge_row = (const int*)d_in[2];
    const int*   edge_col = (const int*)d_in[3];
    const float* edge_val = (const float*)d_in[4];
    float* out = (float*)d_out;

    const size_t H16_BYTES = (size_t)N_NODES * EMB_DIM * sizeof(__half);  // 38.4 MB

    char* ws = (char*)d_ws;
    __half* hA     = (__half*)ws;                      ws += H16_BYTES;
    __half* hB     = (__half*)ws;                      ws += H16_BYTES;
    u64*    csr    = (u64*)ws;                         ws += (size_t)NNZ * 8;
    int*   row_ptr = (int*)ws;                         ws += (size_t)(N_NODES + 4) * 4;
    int*   counts  = (int*)ws;                         ws += (size_t)N_NODES * 4;
    int*   partials= (int*)ws;                         ws += 4096;
    const size_t REQUIRED = (size_t)(ws - (char*)d_ws);

    const int blk     = 256;
    const int n4      = N_NODES * (EMB_DIM / 4);
    const int grid_n4 = (n4 + blk - 1) / blk;

    if (ws_size >= REQUIRED) {
        // ---- build packed, row-sorted CSR (arena partition + fine scatter) ----
        // counts[0..NCOARSE): bin cursors/counts; partials: cbase[0..NCOARSE]
        // arena reuses hA/hB region (57.6 MB <= 76.8 MB), dead before init.
        u64* arena = (u64*)hA;
        zero_int_kernel<<<1, 1024, 0, stream>>>(counts, NCOARSE);
        partition_arena<<<P1_BLOCKS, P1_THREADS, 0, stream>>>(
            edge_row, edge_col, edge_val, counts, arena);
        arena_scan<<<1, 1024, 0, stream>>>(counts, partials);
        fine_scatter<<<NCOARSE, 1024, FS_SHMEM, stream>>>(partials, counts, arena,
                                                          csr, row_ptr);
        // ---- propagate: h0 -> h1 -> h2 -> fused final combine ----
        init16_kernel<<<grid_n4, blk, 0, stream>>>(
            (const float4*)user_emb, (const float4*)item_emb, (uint2*)hA);
        const int grid_sp = (int)(((long long)(N_NODES / 4) * 64) / blk);  // 18,750
        spmm_mid_kernel<<<grid_sp, blk, 0, stream>>>(row_ptr, csr, hA, hB); // h1
        spmm_mid_kernel<<<grid_sp, blk, 0, stream>>>(row_ptr, csr, hB, hA); // h2 (over h0)
        spmm_last_kernel<<<grid_sp, blk, 0, stream>>>(
            row_ptr, csr, hA /*h2*/, hB /*h1*/, user_emb, item_emb, out);
    } else {
        // fallback: fp32 push path (needs only 2 * 76.8 MB)
        const float scales[3] = {1.0f, 1.0f, 0.25f};
        float* hA32 = (float*)d_ws;
        float* hB32 = hA32 + (size_t)N_NODES * EMB_DIM;
        init32_kernel<<<grid_n4, blk, 0, stream>>>(
            (const float4*)user_emb, (const float4*)item_emb, (float4*)hA32, (float4*)out);
        float* h = hA32; float* hn = hB32;
        const int grid_sp = (int)(((long long)NNZ * 64) / blk);
        for (int layer = 0; layer < 3; ++layer) {
            zero4_kernel<<<grid_n4, blk, 0, stream>>>((float4*)hn);
            spmm_push_kernel<<<grid_sp, blk, 0, stream>>>(edge_row, edge_col, edge_val, h, hn);
            acc_kernel<<<grid_n4, blk, 0, stream>>>((float4*)out, (const float4*)hn, scales[layer]);
            float* t = h; h = hn; hn = t;
        }
    }
}